// Round 11
// baseline (150.137 us; speedup 1.0000x reference)
//
#include <hip/hip_runtime.h>
#include <hip/hip_bf16.h>

#define HID 768
#define NHEADS 12
#define HD 64
#define INTER 1152
#define SEQ 2048
#define NB 2
#define ROWS (NB * SEQ)   // 4096
#define QTA 64            // queries per attention block
#define KTA 192           // key panel: QTA + 2*64

typedef __attribute__((ext_vector_type(8))) short bf16x8;
typedef __attribute__((ext_vector_type(4))) float f32x4;

__device__ __forceinline__ unsigned short f2bf(float f) {
    union { float f; unsigned int i; } c; c.f = f;
    unsigned int b = c.i;
    b += 0x7FFFu + ((b >> 16) & 1u);   // round-to-nearest-even
    return (unsigned short)(b >> 16);
}
__device__ __forceinline__ void gload16(const void* g, void* l) {
    __builtin_amdgcn_global_load_lds((const __attribute__((address_space(1))) unsigned int*)g,
                                     (__attribute__((address_space(3))) unsigned int*)l,
                                     16, 0, 0);
}

// ---- merged: rmsnorm1 + weight transposes (wi interleaved) + rope table --
__device__ __forceinline__ void wt_tile(const float* __restrict__ W,
                                        unsigned short* __restrict__ Wt,
                                        int K, int N, int bx, int by,
                                        float (*t)[33]) {
    int tx = threadIdx.x & 31, ty = threadIdx.x >> 5;
    #pragma unroll
    for (int i = 0; i < 4; ++i)
        t[ty + i * 8][tx] = W[(size_t)(by * 32 + ty + i * 8) * N + bx * 32 + tx];
    __syncthreads();
    #pragma unroll
    for (int i = 0; i < 4; ++i)
        Wt[(size_t)(bx * 32 + ty + i * 8) * K + by * 32 + tx] = f2bf(t[tx][ty + i * 8]);
}

// wi variant: output row n -> interleaved row ((n>>4)<<5) + p*16 + (n&15)
__device__ __forceinline__ void wt_tile_i(const float* __restrict__ W,
                                          unsigned short* __restrict__ Wt,
                                          int p, int bx, int by,
                                          float (*t)[33]) {
    int tx = threadIdx.x & 31, ty = threadIdx.x >> 5;
    #pragma unroll
    for (int i = 0; i < 4; ++i)
        t[ty + i * 8][tx] = W[(size_t)(by * 32 + ty + i * 8) * INTER + bx * 32 + tx];
    __syncthreads();
    #pragma unroll
    for (int i = 0; i < 4; ++i) {
        int n = bx * 32 + ty + i * 8;
        int ri = ((n >> 4) << 5) + p * 16 + (n & 15);
        Wt[(size_t)ri * 768 + by * 32 + tx] = f2bf(t[tx][ty + i * 8]);
    }
}

__global__ __launch_bounds__(256) void prep_rms_kernel(const float* __restrict__ x,
                                                       const float* __restrict__ g,
                                                       unsigned short* __restrict__ hbf,
                                                       const float* __restrict__ wqkv,
                                                       const float* __restrict__ woa,
                                                       const float* __restrict__ wi0,
                                                       const float* __restrict__ wi1,
                                                       const float* __restrict__ wom,
                                                       unsigned short* __restrict__ wqkvT,
                                                       unsigned short* __restrict__ woaT,
                                                       unsigned short* __restrict__ wiT,
                                                       unsigned short* __restrict__ womT,
                                                       float2* __restrict__ rtab) {
    __shared__ float t[32][33];
    __shared__ float red[4];
    int id = blockIdx.x;
    int tid = threadIdx.x;
    if (id < 4096) {
        const float* xr = x + (size_t)id * HID;
        unsigned short* orow = hbf + (size_t)id * HID;
        float v0 = xr[tid], v1 = xr[tid + 256], v2 = xr[tid + 512];
        float s = v0 * v0 + v1 * v1 + v2 * v2;
        #pragma unroll
        for (int m = 32; m >= 1; m >>= 1) s += __shfl_xor(s, m, 64);
        if ((tid & 63) == 0) red[tid >> 6] = s;
        __syncthreads();
        float tot = red[0] + red[1] + red[2] + red[3];
        float inv = rsqrtf(tot * (1.0f / HID) + 1e-5f);
        orow[tid]       = f2bf(v0 * inv * g[tid]);
        orow[tid + 256] = f2bf(v1 * inv * g[tid + 256]);
        orow[tid + 512] = f2bf(v2 * inv * g[tid + 512]);
        return;
    }
    id -= 4096;
    if (id < 1728)       wt_tile(wqkv, wqkvT, 768, 2304, id % 72, id / 72, t);
    else if (id < 2304)  { id -= 1728; wt_tile(woa, woaT, 768, 768, id % 24, id / 24, t); }
    else if (id < 3168)  { id -= 2304; wt_tile_i(wi0, wiT, 0, id % 36, id / 36, t); }
    else if (id < 4032)  { id -= 3168; wt_tile_i(wi1, wiT, 1, id % 36, id / 36, t); }
    else if (id < 4896)  { id -= 4032; wt_tile(wom, womT, 1152, 768, id % 24, id / 24, t); }
    else {
        int idx = (id - 4896) * 256 + tid;   // 65536 = 2048*32
        int s = idx >> 5, fi = idx & 31;
        float ang = (float)s * exp2f(-(float)fi * 0.41524101186f);
        float sn, cs;
        sincosf(ang, &sn, &cs);
        rtab[idx] = make_float2(cs, sn);
    }
}

// ---------------- RMSNorm (standalone, for x1 -> h2) ----------------------
__global__ __launch_bounds__(256) void rmsnorm_kernel(const float* __restrict__ x,
                                                      const float* __restrict__ g,
                                                      unsigned short* __restrict__ out) {
    int row = blockIdx.x;
    const float* xr = x + (size_t)row * HID;
    unsigned short* orow = out + (size_t)row * HID;
    int tid = threadIdx.x;
    float v0 = xr[tid], v1 = xr[tid + 256], v2 = xr[tid + 512];
    float s = v0 * v0 + v1 * v1 + v2 * v2;
    #pragma unroll
    for (int m = 32; m >= 1; m >>= 1) s += __shfl_xor(s, m, 64);
    __shared__ float red[4];
    if ((tid & 63) == 0) red[tid >> 6] = s;
    __syncthreads();
    float tot = red[0] + red[1] + red[2] + red[3];
    float inv = rsqrtf(tot * (1.0f / HID) + 1e-5f);
    orow[tid]       = f2bf(v0 * inv * g[tid]);
    orow[tid + 256] = f2bf(v1 * inv * g[tid + 256]);
    orow[tid + 512] = f2bf(v2 * inv * g[tid + 512]);
}

// ------ wo GEMM: 128x64 tile, BK=128, 48 KB LDS, resid + fp32 out --------
__global__ __launch_bounds__(256) void gemm_wo128(const unsigned short* __restrict__ A,
                                                  const unsigned short* __restrict__ Bt,
                                                  const float* __restrict__ resid,
                                                  float* __restrict__ C,
                                                  int N, int K) {
    __shared__ unsigned short As[128 * 128];   // 32 KB
    __shared__ unsigned short Bs[64 * 128];    // 16 KB
    int nbx = N >> 6;
    int nwg = gridDim.x;
    int bid = blockIdx.x;
    int id2 = (bid & 7) * (nwg >> 3) + (bid >> 3);
    int col0 = (id2 % nbx) * 64, row0 = (id2 / nbx) * 128;
    int tid = threadIdx.x;
    int wave = tid >> 6, lane = tid & 63;
    int fr = lane & 15, fq = lane >> 4;

    const size_t strideA = (size_t)K * 2;
    const char* Ab = (const char*)A;
    const char* Bb = (const char*)Bt;

    f32x4 acc[2][4];
    #pragma unroll
    for (int m = 0; m < 2; ++m)
        #pragma unroll
        for (int n = 0; n < 4; ++n)
            acc[m][n] = (f32x4){0.f, 0.f, 0.f, 0.f};

    int nt = K >> 7;
    for (int t = 0; t < nt; ++t) {
        int k0 = t << 7;
        #pragma unroll
        for (int r = 0; r < 8; ++r) {
            int L = r * 4096 + tid * 16;
            int row = L >> 8;
            int ss = ((L >> 4) & 15) ^ (row & 15);
            gload16(Ab + (size_t)(row0 + row) * strideA + (size_t)k0 * 2 + ss * 16,
                    (char*)As + L);
        }
        #pragma unroll
        for (int r = 0; r < 4; ++r) {
            int L = r * 4096 + tid * 16;
            int row = L >> 8;
            int ss = ((L >> 4) & 15) ^ (row & 15);
            gload16(Bb + (size_t)(col0 + row) * strideA + (size_t)k0 * 2 + ss * 16,
                    (char*)Bs + L);
        }
        __syncthreads();
        #pragma unroll
        for (int kk = 0; kk < 4; ++kk) {
            bf16x8 af[2], bf[4];
            #pragma unroll
            for (int m = 0; m < 2; ++m) {
                int rowa = wave * 32 + m * 16 + fr;
                af[m] = *(const bf16x8*)&As[rowa * 128 + ((kk * 4 + fq) ^ (rowa & 15)) * 8];
            }
            #pragma unroll
            for (int n = 0; n < 4; ++n) {
                int rowb = n * 16 + fr;
                bf[n] = *(const bf16x8*)&Bs[rowb * 128 + ((kk * 4 + fq) ^ (rowb & 15)) * 8];
            }
            #pragma unroll
            for (int m = 0; m < 2; ++m)
                #pragma unroll
                for (int n = 0; n < 4; ++n)
                    acc[m][n] = __builtin_amdgcn_mfma_f32_16x16x32_bf16(af[m], bf[n], acc[m][n], 0, 0, 0);
        }
        __syncthreads();
    }

    #pragma unroll
    for (int m = 0; m < 2; ++m)
        #pragma unroll
        for (int j = 0; j < 4; ++j) {
            size_t r = (size_t)(row0 + wave * 32 + m * 16 + fq * 4 + j);
            #pragma unroll
            for (int n = 0; n < 4; ++n) {
                size_t idx = r * N + (col0 + n * 16 + fr);
                C[idx] = acc[m][n][j] + resid[idx];
            }
        }
}

// ------ fused qkv GEMM: 128x128 tile, BK=64, 2x2 waves, acc[4][4] --------
// 16 MFMA : 8 ds_read per wave K32-substep (m97 ratio). Grid 576.
__global__ __launch_bounds__(256) void gemm_qkv(const unsigned short* __restrict__ A,
                                                const unsigned short* __restrict__ Bt,
                                                const float2* __restrict__ rtab,
                                                unsigned short* __restrict__ Qb,
                                                unsigned short* __restrict__ Kb,
                                                unsigned short* __restrict__ Vt) {
    __shared__ unsigned short As[128 * 64];   // 16 KB
    __shared__ unsigned short Bs[128 * 64];   // 16 KB
    int bid = blockIdx.x;                      // 576 blocks
    int id2 = (bid & 7) * 72 + (bid >> 3);
    int col0 = (id2 % 18) * 128, row0 = (id2 / 18) * 128;
    int tid = threadIdx.x;
    int wave = tid >> 6, lane = tid & 63;
    int wr = wave >> 1, wc = wave & 1;
    int fr = lane & 15, fq = lane >> 4;
    int type = col0 / 768;              // 0=q, 1=k, 2=v (tile fully inside one)
    int head2 = (col0 % 768) >> 6;      // base head (tile spans heads head2, head2+1)
    int b = row0 >> 11;
    int s0 = row0 & 2047;

    const size_t strideA = (size_t)768 * 2;
    const char* Ab = (const char*)A;
    const char* Bb = (const char*)Bt;

    f32x4 acc[4][4];
    #pragma unroll
    for (int m = 0; m < 4; ++m)
        #pragma unroll
        for (int n = 0; n < 4; ++n)
            acc[m][n] = (f32x4){0.f, 0.f, 0.f, 0.f};

    for (int t = 0; t < 12; ++t) {
        int k0 = t << 6;
        #pragma unroll
        for (int r = 0; r < 4; ++r) {
            int L = r * 4096 + tid * 16;      // 128 rows x 128 B
            int row = L >> 7;
            int ss = ((L >> 4) & 7) ^ (row & 7);
            gload16(Ab + (size_t)(row0 + row) * strideA + (size_t)k0 * 2 + ss * 16,
                    (char*)As + L);
            gload16(Bb + (size_t)(col0 + row) * strideA + (size_t)k0 * 2 + ss * 16,
                    (char*)Bs + L);
        }
        __syncthreads();
        #pragma unroll
        for (int kk = 0; kk < 2; ++kk) {
            bf16x8 af[4], bf[4];
            #pragma unroll
            for (int m = 0; m < 4; ++m) {
                int rowa = wr * 64 + m * 16 + fr;
                af[m] = *(const bf16x8*)&As[rowa * 64 + ((kk * 4 + fq) ^ (rowa & 7)) * 8];
            }
            #pragma unroll
            for (int n = 0; n < 4; ++n) {
                int rowb = wc * 64 + n * 16 + fr;
                bf[n] = *(const bf16x8*)&Bs[rowb * 64 + ((kk * 4 + fq) ^ (rowb & 7)) * 8];
            }
            #pragma unroll
            for (int m = 0; m < 4; ++m)
                #pragma unroll
                for (int n = 0; n < 4; ++n)
                    acc[m][n] = __builtin_amdgcn_mfma_f32_16x16x32_bf16(af[m], bf[n], acc[m][n], 0, 0, 0);
        }
        __syncthreads();
    }

    if (type < 2) {
        int head = head2 + wc;
        unsigned short* P = (type == 0 ? Qb : Kb) + ((size_t)(b * NHEADS + head) * SEQ) * 64;
        #pragma unroll
        for (int m = 0; m < 4; ++m)
            #pragma unroll
            for (int n = 0; n < 4; ++n) {
                int d = n * 16 + fr;
                int fi = d & 31;
                #pragma unroll
                for (int j = 0; j < 4; ++j) {
                    int s = s0 + wr * 64 + m * 16 + fq * 4 + j;
                    float2 cs = rtab[s * 32 + fi];
                    float val = acc[m][n][j], par = acc[m][n ^ 2][j];
                    float o = (d < 32) ? val * cs.x - par * cs.y
                                       : val * cs.x + par * cs.y;
                    P[(size_t)s * 64 + d] = f2bf(o);
                }
            }
    } else {
        // V: two per-head passes through one 17.4 KB LDS buffer (stride 136)
        unsigned short* vt = As;
        #pragma unroll
        for (int hp = 0; hp < 2; ++hp) {
            __syncthreads();
            if (wc == hp) {
                #pragma unroll
                for (int m = 0; m < 4; ++m)
                    #pragma unroll
                    for (int n = 0; n < 4; ++n) {
                        int d = n * 16 + fr;
                        #pragma unroll
                        for (int j = 0; j < 4; ++j)
                            vt[d * 136 + wr * 64 + m * 16 + fq * 4 + j] = f2bf(acc[m][n][j]);
                    }
            }
            __syncthreads();
            int head = head2 + hp;
            int d = tid >> 2, sg = tid & 3;
            unsigned short* vrow = Vt + (((size_t)(b * NHEADS + head)) * 64 + d) * SEQ + s0 + sg * 32;
            #pragma unroll
            for (int i = 0; i < 4; ++i)
                *(bf16x8*)(vrow + i * 8) = *(const bf16x8*)&vt[d * 136 + sg * 32 + i * 8];
        }
    }
}

// ------ fused FFN-in: 128x128 tile over interleaved [wi0|wi1], BK=64 -----
// Fragment pairs (even,odd) = (wi0 g, wi1 g) in-wave -> gated GELU in-reg.
__global__ __launch_bounds__(256) void gemm_ffn(const unsigned short* __restrict__ A,
                                                const unsigned short* __restrict__ Bt,
                                                unsigned short* __restrict__ O) {
    __shared__ unsigned short As[128 * 64];   // 16 KB
    __shared__ unsigned short Bs[128 * 64];   // 16 KB
    int bid = blockIdx.x;                      // 576 blocks
    int id2 = (bid & 7) * 72 + (bid >> 3);
    int col0 = (id2 % 18) * 128, row0 = (id2 / 18) * 128;
    int tid = threadIdx.x;
    int wave = tid >> 6, lane = tid & 63;
    int wr = wave >> 1, wc = wave & 1;
    int fr = lane & 15, fq = lane >> 4;

    const size_t strideA = (size_t)768 * 2;
    const char* Ab = (const char*)A;
    const char* Bb = (const char*)Bt;

    f32x4 acc[4][4];
    #pragma unroll
    for (int m = 0; m < 4; ++m)
        #pragma unroll
        for (int n = 0; n < 4; ++n)
            acc[m][n] = (f32x4){0.f, 0.f, 0.f, 0.f};

    for (int t = 0; t < 12; ++t) {
        int k0 = t << 6;
        #pragma unroll
        for (int r = 0; r < 4; ++r) {
            int L = r * 4096 + tid * 16;
            int row = L >> 7;
            int ss = ((L >> 4) & 7) ^ (row & 7);
            gload16(Ab + (size_t)(row0 + row) * strideA + (size_t)k0 * 2 + ss * 16,
                    (char*)As + L);
            gload16(Bb + (size_t)(col0 + row) * strideA + (size_t)k0 * 2 + ss * 16,
                    (char*)Bs + L);
        }
        __syncthreads();
        #pragma unroll
        for (int kk = 0; kk < 2; ++kk) {
            bf16x8 af[4], bf[4];
            #pragma unroll
            for (int m = 0; m < 4; ++m) {
                int rowa = wr * 64 + m * 16 + fr;
                af[m] = *(const bf16x8*)&As[rowa * 64 + ((kk * 4 + fq) ^ (rowa & 7)) * 8];
            }
            #pragma unroll
            for (int n = 0; n < 4; ++n) {
                int rowb = wc * 64 + n * 16 + fr;
                bf[n] = *(const bf16x8*)&Bs[rowb * 64 + ((kk * 4 + fq) ^ (rowb & 7)) * 8];
            }
            #pragma unroll
            for (int m = 0; m < 4; ++m)
                #pragma unroll
                for (int n = 0; n < 4; ++n)
                    acc[m][n] = __builtin_amdgcn_mfma_f32_16x16x32_bf16(af[m], bf[n], acc[m][n], 0, 0, 0);
        }
        __syncthreads();
    }

    // gelu(acc[m][even]) * acc[m][odd]; out col = col0/2 + wc*32 + (nl>>1)*16 + fr
    #pragma unroll
    for (int m = 0; m < 4; ++m)
        #pragma unroll
        for (int nl = 0; nl < 4; nl += 2)
            #pragma unroll
            for (int j = 0; j < 4; ++j) {
                int r = row0 + wr * 64 + m * 16 + fq * 4 + j;
                float xa = acc[m][nl][j];
                float tn = tanhf(0.7978845608028654f * (xa + 0.044715f * xa * xa * xa));
                float gv = 0.5f * xa * (1.f + tn) * acc[m][nl + 1][j];
                int col = (col0 >> 1) + wc * 32 + (nl >> 1) * 16 + fr;
                O[(size_t)r * INTER + col] = f2bf(gv);
            }
}

// ---------------- MFMA sliding-window attention ---------------------------
__global__ __launch_bounds__(256) void attn_mfma(const unsigned short* __restrict__ Qb,
                                                 const unsigned short* __restrict__ Kb,
                                                 const unsigned short* __restrict__ Vt,
                                                 const int* __restrict__ pmask,
                                                 unsigned short* __restrict__ ao) {
    __shared__ unsigned short Ks[KTA * 64];     // 24576 B; becomes Ps after QK^T
    __shared__ unsigned short Vs[64 * KTA];     // 24576 B
    __shared__ float pmsk[KTA];

    int bid = blockIdx.x;
    int qt = bid & 31;
    int h  = (bid >> 5) % NHEADS;
    int b  = bid / (32 * NHEADS);
    int bh = b * NHEADS + h;
    int q0 = qt * QTA;
    int kstart = q0 - 64;
    int tid = threadIdx.x;
    int wave = tid >> 6, lane = tid & 63;
    int fr = lane & 15, fq = lane >> 4;

    const unsigned short* Kg = Kb + ((size_t)bh * SEQ) * 64;
    const unsigned short* Vg = Vt + ((size_t)bh * 64) * SEQ;

    const unsigned short* Qg = Qb + ((size_t)bh * SEQ + q0 + wave * 16 + fr) * 64 + fq * 8;
    bf16x8 qf0 = *(const bf16x8*)(Qg);
    bf16x8 qf1 = *(const bf16x8*)(Qg + 32);
    if (tid < KTA) {
        int k = kstart + tid;
        pmsk[tid] = (k >= 0 && k < SEQ) ? (1.0f - (float)pmask[b * SEQ + k]) * -1e9f
                                        : -1e9f;
    }

    bool interior = (qt != 0) && (qt != 31);
    if (interior) {
        #pragma unroll
        for (int r = 0; r < 6; ++r) {
            int c = r * 256 + tid;
            int row = c >> 3, slot = c & 7;
            int ss = slot ^ (row & 7);
            gload16(Kg + (size_t)(kstart + row) * 64 + ss * 8, (char*)Ks + c * 16);
        }
        #pragma unroll
        for (int r = 0; r < 6; ++r) {
            int c = r * 256 + tid;
            int d = c / 24, slot = c - d * 24;
            int ss = (slot & ~7) | ((slot & 7) ^ (d & 7));
            gload16(Vg + (size_t)d * SEQ + kstart + ss * 8, (char*)Vs + c * 16);
        }
    } else {
        #pragma unroll
        for (int r = 0; r < 6; ++r) {
            int c = r * 256 + tid;
            int row = c >> 3, slot = c & 7;
            int ss = slot ^ (row & 7);
            int sk = kstart + row;
            bf16x8 val = {0, 0, 0, 0, 0, 0, 0, 0};
            if (sk >= 0 && sk < SEQ)
                val = *(const bf16x8*)(Kg + (size_t)sk * 64 + ss * 8);
            *(bf16x8*)((char*)Ks + c * 16) = val;
        }
        #pragma unroll
        for (int r = 0; r < 6; ++r) {
            int c = r * 256 + tid;
            int d = c / 24, slot = c - d * 24;
            int ss = (slot & ~7) | ((slot & 7) ^ (d & 7));
            int start = kstart + ss * 8;
            bf16x8 val = {0, 0, 0, 0, 0, 0, 0, 0};
            if (start >= 0 && start + 8 <= SEQ)
                val = *(const bf16x8*)(Vg + (size_t)d * SEQ + start);
            *(bf16x8*)((char*)Vs + c * 16) = val;
        }
    }
    __syncthreads();

    f32x4 sc[9];
    #pragma unroll
    for (int ni = 0; ni < 9; ++ni) sc[ni] = (f32x4){0.f, 0.f, 0.f, 0.f};
    #pragma unroll
    for (int ni = 0; ni < 9; ++ni) {
        int row = (wave + ni) * 16 + fr;
        int base = row * 64;
        bf16x8 k0 = *(const bf16x8*)&Ks[base + ((fq)     ^ (row & 7)) * 8];
        bf16x8 k1 = *(const bf16x8*)&Ks[base + ((4 + fq) ^ (row & 7)) * 8];
        sc[ni] = __builtin_amdgcn_mfma_f32_16x16x32_bf16(qf0, k0, sc[ni], 0, 0, 0);
        sc[ni] = __builtin_amdgcn_mfma_f32_16x16x32_bf16(qf1, k1, sc[ni], 0, 0, 0);
    }

    int qrow_base = q0 + wave * 16 + fq * 4;
    float mj[4] = {-1e30f, -1e30f, -1e30f, -1e30f}, sj[4];
    #pragma unroll
    for (int ni = 0; ni < 9; ++ni) {
        int kp = (wave + ni) * 16 + fr;
        int k = kstart + kp;
        float pm = pmsk[kp];
        #pragma unroll
        for (int j = 0; j < 4; ++j) {
            int diff = qrow_base + j - k;
            float s = sc[ni][j] * 0.125f + pm;
            if (diff > 64 || diff < -64) s = -1e30f;
            sc[ni][j] = s;
            mj[j] = fmaxf(mj[j], s);
        }
    }
    #pragma unroll
    for (int j = 0; j < 4; ++j) {
        #pragma unroll
        for (int mk = 1; mk < 16; mk <<= 1)
            mj[j] = fmaxf(mj[j], __shfl_xor(mj[j], mk, 16));
        sj[j] = 0.f;
    }
    #pragma unroll
    for (int ni = 0; ni < 9; ++ni)
        #pragma unroll
        for (int j = 0; j < 4; ++j) {
            float e = expf(sc[ni][j] - mj[j]);
            sc[ni][j] = e;
            sj[j] += e;
        }
    #pragma unroll
    for (int j = 0; j < 4; ++j)
        #pragma unroll
        for (int mk = 1; mk < 16; mk <<= 1)
            sj[j] += __shfl_xor(sj[j], mk, 16);

    __syncthreads();   // all waves done reading Ks -> safe to alias as Ps

    unsigned short* Pw = Ks + wave * 16 * KTA;
    #pragma unroll
    for (int ni = 0; ni < 9; ++ni) {
        int n = wave + ni;
        int slot = n * 2 + (fr >> 3);
        #pragma unroll
        for (int j = 0; j < 4; ++j) {
            int row = fq * 4 + j;
            int ss = (slot & ~7) | ((slot & 7) ^ (row & 7));
            Pw[row * KTA + ss * 8 + (fr & 7)] = f2bf(sc[ni][j]);
        }
    }
    #pragma unroll
    for (int n = 0; n < 12; ++n) {
        if (n >= wave && n <= wave + 8) continue;
        int slot = n * 2 + (fr >> 3);
        #pragma unroll
        for (int j = 0; j < 4; ++j) {
            int row = fq * 4 + j;
            int ss = (slot & ~7) | ((slot & 7) ^ (row & 7));
            Pw[row * KTA + ss * 8 + (fr & 7)] = 0;
        }
    }

    f32x4 oacc[4];
    #pragma unroll
    for (int n = 0; n < 4; ++n) oacc[n] = (f32x4){0.f, 0.f, 0.f, 0.f};
    int kt0 = wave >> 1;
    #pragma unroll
    for (int ki = 0; ki < 5; ++ki) {
        int slot = (kt0 + ki) * 4 + fq;
        int ssp = (slot & ~7) | ((slot & 7) ^ (fr & 7));
        bf16x8 pa = *(const bf16x8*)&Pw[fr * KTA + ssp * 8];
        #pragma unroll
        for (int n = 0; n < 4; ++n) {
            int d = n * 16 + fr;
            int ssv = (slot & ~7) | ((slot & 7) ^ (d & 7));
            bf16x8 vf = *(const bf16x8*)&Vs[d * KTA + ssv * 8];
            oacc[n] = __builtin_amdgcn_mfma_f32_16x16x32_bf16(pa, vf, oacc[n], 0, 0, 0);
        }
    }

    unsigned short* aob = ao + ((size_t)(b * SEQ + qrow_base)) * HID + h * 64;
    float rs[4];
    #pragma unroll
    for (int j = 0; j < 4; ++j) rs[j] = 1.0f / sj[j];
    #pragma unroll
    for (int n = 0; n < 4; ++n)
        #pragma unroll
        for (int j = 0; j < 4; ++j)
            aob[(size_t)j * HID + n * 16 + fr] = f2bf(oacc[n][j] * rs[j]);
}

extern "C" void kernel_launch(void* const* d_in, const int* in_sizes, int n_in,
                              void* d_out, int out_size, void* d_ws, size_t ws_size,
                              hipStream_t stream) {
    const float* x       = (const float*)d_in[0];
    const int*   pmask   = (const int*)d_in[1];
    const float* wqkv    = (const float*)d_in[2];
    const float* wo_attn = (const float*)d_in[3];
    const float* wi0     = (const float*)d_in[4];
    const float* wi1     = (const float*)d_in[5];
    const float* wo_mlp  = (const float*)d_in[6];
    const float* g_attn  = (const float*)d_in[7];
    const float* g_mlp   = (const float*)d_in[8];
    float* out = (float*)d_out;

    char* w = (char*)d_ws;
    unsigned short* hbf   = (unsigned short*)(w);              // 6291456 B
    unsigned short* aobf  = (unsigned short*)(w + 6291456);    // 6291456 B
    unsigned short* Qb    = (unsigned short*)(w + 12582912);   // 6291456 B
    unsigned short* Kb    = (unsigned short*)(w + 18874368);   // 6291456 B
    unsigned short* Vt    = (unsigned short*)(w + 25165824);   // 6291456 B
    unsigned short* mgate = (unsigned short*)(w + 31457280);   // 9437184 B
    float2*         rtab  = (float2*)(w + 40894464);           // 524288 B
    unsigned short* wqkvT = (unsigned short*)(w + 41418752);   // [2304][768]
    unsigned short* woaT  = (unsigned short*)(w + 44957696);   // [768][768]
    unsigned short* wiT   = (unsigned short*)(w + 46137344);   // [2304][768] interleaved
    unsigned short* womT  = (unsigned short*)(w + 49676288);   // [768][1152]

    // 0. merged: rmsnorm1 + weight transposes (wi interleaved) + rope table
    prep_rms_kernel<<<4096 + 5152, 256, 0, stream>>>(x, g_attn, hbf,
                                                     wqkv, wo_attn, wi0, wi1, wo_mlp,
                                                     wqkvT, woaT, wiT, womT, rtab);
    // 1. fused qkv GEMM (128^2 tile) + RoPE + layout -> Qb, Kb, Vt
    gemm_qkv<<<576, 256, 0, stream>>>(hbf, wqkvT, rtab, Qb, Kb, Vt);
    // 2. MFMA sliding-window attention
    attn_mfma<<<NB * NHEADS * (SEQ / QTA), 256, 0, stream>>>(Qb, Kb, Vt, pmask, aobf);
    // 3. x1 = x + ao @ wo_attn  -> d_out
    gemm_wo128<<<384, 256, 0, stream>>>(aobf, woaT, x, out, 768, 768);
    // 4. h = rmsnorm(x1, g_mlp)
    rmsnorm_kernel<<<ROWS, 256, 0, stream>>>(out, g_mlp, hbf);
    // 5. mgate = gelu(h@wi0) * (h@wi1)  (128^2 interleaved tile)
    gemm_ffn<<<576, 256, 0, stream>>>(hbf, wiT, mgate);
    // 6. out = x1 + mgate @ wo_mlp
    gemm_wo128<<<384, 256, 0, stream>>>(mgate, womT, out, out, 768, 1152);
}

// Round 12
// 114.013 us; speedup vs baseline: 1.3168x; 1.3168x over previous
//
#include <hip/hip_runtime.h>
#include <hip/hip_bf16.h>

#define HID 768
#define NHEADS 12
#define HD 64
#define INTER 1152
#define SEQ 2048
#define NB 2
#define ROWS (NB * SEQ)   // 4096
#define QTA 64            // queries per attention block
#define KTA 192           // key panel: QTA + 2*64

typedef __attribute__((ext_vector_type(8))) short bf16x8;
typedef __attribute__((ext_vector_type(4))) float f32x4;

__device__ __forceinline__ unsigned short f2bf(float f) {
    union { float f; unsigned int i; } c; c.f = f;
    unsigned int b = c.i;
    b += 0x7FFFu + ((b >> 16) & 1u);   // round-to-nearest-even
    return (unsigned short)(b >> 16);
}
__device__ __forceinline__ void gload16(const void* g, void* l) {
    __builtin_amdgcn_global_load_lds((const __attribute__((address_space(1))) unsigned int*)g,
                                     (__attribute__((address_space(3))) unsigned int*)l,
                                     16, 0, 0);
}

// ---- merged: rmsnorm1 + weight transposes (wi interleaved) + rope table --
__device__ __forceinline__ void wt_tile(const float* __restrict__ W,
                                        unsigned short* __restrict__ Wt,
                                        int K, int N, int bx, int by,
                                        float (*t)[33]) {
    int tx = threadIdx.x & 31, ty = threadIdx.x >> 5;
    #pragma unroll
    for (int i = 0; i < 4; ++i)
        t[ty + i * 8][tx] = W[(size_t)(by * 32 + ty + i * 8) * N + bx * 32 + tx];
    __syncthreads();
    #pragma unroll
    for (int i = 0; i < 4; ++i)
        Wt[(size_t)(bx * 32 + ty + i * 8) * K + by * 32 + tx] = f2bf(t[tx][ty + i * 8]);
}

// wi variant: output row n -> interleaved row ((n>>4)<<5) + p*16 + (n&15)
__device__ __forceinline__ void wt_tile_i(const float* __restrict__ W,
                                          unsigned short* __restrict__ Wt,
                                          int p, int bx, int by,
                                          float (*t)[33]) {
    int tx = threadIdx.x & 31, ty = threadIdx.x >> 5;
    #pragma unroll
    for (int i = 0; i < 4; ++i)
        t[ty + i * 8][tx] = W[(size_t)(by * 32 + ty + i * 8) * INTER + bx * 32 + tx];
    __syncthreads();
    #pragma unroll
    for (int i = 0; i < 4; ++i) {
        int n = bx * 32 + ty + i * 8;
        int ri = ((n >> 4) << 5) + p * 16 + (n & 15);
        Wt[(size_t)ri * 768 + by * 32 + tx] = f2bf(t[tx][ty + i * 8]);
    }
}

__global__ __launch_bounds__(256) void prep_rms_kernel(const float* __restrict__ x,
                                                       const float* __restrict__ g,
                                                       unsigned short* __restrict__ hbf,
                                                       const float* __restrict__ wqkv,
                                                       const float* __restrict__ woa,
                                                       const float* __restrict__ wi0,
                                                       const float* __restrict__ wi1,
                                                       const float* __restrict__ wom,
                                                       unsigned short* __restrict__ wqkvT,
                                                       unsigned short* __restrict__ woaT,
                                                       unsigned short* __restrict__ wiT,
                                                       unsigned short* __restrict__ womT,
                                                       float2* __restrict__ rtab) {
    __shared__ float t[32][33];
    __shared__ float red[4];
    int id = blockIdx.x;
    int tid = threadIdx.x;
    if (id < 4096) {
        const float* xr = x + (size_t)id * HID;
        unsigned short* orow = hbf + (size_t)id * HID;
        float v0 = xr[tid], v1 = xr[tid + 256], v2 = xr[tid + 512];
        float s = v0 * v0 + v1 * v1 + v2 * v2;
        #pragma unroll
        for (int m = 32; m >= 1; m >>= 1) s += __shfl_xor(s, m, 64);
        if ((tid & 63) == 0) red[tid >> 6] = s;
        __syncthreads();
        float tot = red[0] + red[1] + red[2] + red[3];
        float inv = rsqrtf(tot * (1.0f / HID) + 1e-5f);
        orow[tid]       = f2bf(v0 * inv * g[tid]);
        orow[tid + 256] = f2bf(v1 * inv * g[tid + 256]);
        orow[tid + 512] = f2bf(v2 * inv * g[tid + 512]);
        return;
    }
    id -= 4096;
    if (id < 1728)       wt_tile(wqkv, wqkvT, 768, 2304, id % 72, id / 72, t);
    else if (id < 2304)  { id -= 1728; wt_tile(woa, woaT, 768, 768, id % 24, id / 24, t); }
    else if (id < 3168)  { id -= 2304; wt_tile_i(wi0, wiT, 0, id % 36, id / 36, t); }
    else if (id < 4032)  { id -= 3168; wt_tile_i(wi1, wiT, 1, id % 36, id / 36, t); }
    else if (id < 4896)  { id -= 4032; wt_tile(wom, womT, 1152, 768, id % 24, id / 24, t); }
    else {
        int idx = (id - 4896) * 256 + tid;   // 65536 = 2048*32
        int s = idx >> 5, fi = idx & 31;
        float ang = (float)s * exp2f(-(float)fi * 0.41524101186f);
        float sn, cs;
        sincosf(ang, &sn, &cs);
        rtab[idx] = make_float2(cs, sn);
    }
}

// ---------------- RMSNorm (standalone, for x1 -> h2) ----------------------
__global__ __launch_bounds__(256) void rmsnorm_kernel(const float* __restrict__ x,
                                                      const float* __restrict__ g,
                                                      unsigned short* __restrict__ out) {
    int row = blockIdx.x;
    const float* xr = x + (size_t)row * HID;
    unsigned short* orow = out + (size_t)row * HID;
    int tid = threadIdx.x;
    float v0 = xr[tid], v1 = xr[tid + 256], v2 = xr[tid + 512];
    float s = v0 * v0 + v1 * v1 + v2 * v2;
    #pragma unroll
    for (int m = 32; m >= 1; m >>= 1) s += __shfl_xor(s, m, 64);
    __shared__ float red[4];
    if ((tid & 63) == 0) red[tid >> 6] = s;
    __syncthreads();
    float tot = red[0] + red[1] + red[2] + red[3];
    float inv = rsqrtf(tot * (1.0f / HID) + 1e-5f);
    orow[tid]       = f2bf(v0 * inv * g[tid]);
    orow[tid + 256] = f2bf(v1 * inv * g[tid + 256]);
    orow[tid + 512] = f2bf(v2 * inv * g[tid + 512]);
}

// ------ wo GEMM: 128x64 tile, BK=128, 48 KB LDS, resid + fp32 out --------
__global__ __launch_bounds__(256) void gemm_wo128(const unsigned short* __restrict__ A,
                                                  const unsigned short* __restrict__ Bt,
                                                  const float* __restrict__ resid,
                                                  float* __restrict__ C,
                                                  int N, int K) {
    __shared__ unsigned short As[128 * 128];   // 32 KB
    __shared__ unsigned short Bs[64 * 128];    // 16 KB
    int nbx = N >> 6;
    int nwg = gridDim.x;
    int bid = blockIdx.x;
    int id2 = (bid & 7) * (nwg >> 3) + (bid >> 3);
    int col0 = (id2 % nbx) * 64, row0 = (id2 / nbx) * 128;
    int tid = threadIdx.x;
    int wave = tid >> 6, lane = tid & 63;
    int fr = lane & 15, fq = lane >> 4;

    const size_t strideA = (size_t)K * 2;
    const char* Ab = (const char*)A;
    const char* Bb = (const char*)Bt;

    f32x4 acc[2][4];
    #pragma unroll
    for (int m = 0; m < 2; ++m)
        #pragma unroll
        for (int n = 0; n < 4; ++n)
            acc[m][n] = (f32x4){0.f, 0.f, 0.f, 0.f};

    int nt = K >> 7;
    for (int t = 0; t < nt; ++t) {
        int k0 = t << 7;
        #pragma unroll
        for (int r = 0; r < 8; ++r) {
            int L = r * 4096 + tid * 16;
            int row = L >> 8;
            int ss = ((L >> 4) & 15) ^ (row & 15);
            gload16(Ab + (size_t)(row0 + row) * strideA + (size_t)k0 * 2 + ss * 16,
                    (char*)As + L);
        }
        #pragma unroll
        for (int r = 0; r < 4; ++r) {
            int L = r * 4096 + tid * 16;
            int row = L >> 8;
            int ss = ((L >> 4) & 15) ^ (row & 15);
            gload16(Bb + (size_t)(col0 + row) * strideA + (size_t)k0 * 2 + ss * 16,
                    (char*)Bs + L);
        }
        __syncthreads();
        #pragma unroll
        for (int kk = 0; kk < 4; ++kk) {
            bf16x8 af[2], bf[4];
            #pragma unroll
            for (int m = 0; m < 2; ++m) {
                int rowa = wave * 32 + m * 16 + fr;
                af[m] = *(const bf16x8*)&As[rowa * 128 + ((kk * 4 + fq) ^ (rowa & 15)) * 8];
            }
            #pragma unroll
            for (int n = 0; n < 4; ++n) {
                int rowb = n * 16 + fr;
                bf[n] = *(const bf16x8*)&Bs[rowb * 128 + ((kk * 4 + fq) ^ (rowb & 15)) * 8];
            }
            #pragma unroll
            for (int m = 0; m < 2; ++m)
                #pragma unroll
                for (int n = 0; n < 4; ++n)
                    acc[m][n] = __builtin_amdgcn_mfma_f32_16x16x32_bf16(af[m], bf[n], acc[m][n], 0, 0, 0);
        }
        __syncthreads();
    }

    #pragma unroll
    for (int m = 0; m < 2; ++m)
        #pragma unroll
        for (int j = 0; j < 4; ++j) {
            size_t r = (size_t)(row0 + wave * 32 + m * 16 + fq * 4 + j);
            #pragma unroll
            for (int n = 0; n < 4; ++n) {
                size_t idx = r * N + (col0 + n * 16 + fr);
                C[idx] = acc[m][n][j] + resid[idx];
            }
        }
}

// ------ fused qkv GEMM: 128x64 tile, BK=128 (48 KB LDS) ------------------
__global__ __launch_bounds__(256) void gemm_qkv128(const unsigned short* __restrict__ A,
                                                   const unsigned short* __restrict__ Bt,
                                                   const float2* __restrict__ rtab,
                                                   unsigned short* __restrict__ Qb,
                                                   unsigned short* __restrict__ Kb,
                                                   unsigned short* __restrict__ Vt) {
    __shared__ unsigned short As[128 * 128];   // 32 KB
    __shared__ unsigned short Bs[64 * 128];    // 16 KB
    int bid = blockIdx.x;                       // 1152 blocks
    int id2 = (bid & 7) * 144 + (bid >> 3);
    int col0 = (id2 % 36) * 64, row0 = (id2 / 36) * 128;
    int tid = threadIdx.x;
    int wave = tid >> 6, lane = tid & 63;
    int fr = lane & 15, fq = lane >> 4;
    int type = col0 / 768;              // 0=q, 1=k, 2=v
    int h = (col0 % 768) >> 6;
    int b = row0 >> 11;
    int s0 = row0 & 2047;
    int bh = b * NHEADS + h;

    const size_t strideA = (size_t)768 * 2;
    const char* Ab = (const char*)A;
    const char* Bb = (const char*)Bt;

    f32x4 acc[2][4];
    #pragma unroll
    for (int m = 0; m < 2; ++m)
        #pragma unroll
        for (int n = 0; n < 4; ++n)
            acc[m][n] = (f32x4){0.f, 0.f, 0.f, 0.f};

    for (int t = 0; t < 6; ++t) {
        int k0 = t << 7;
        #pragma unroll
        for (int r = 0; r < 8; ++r) {
            int L = r * 4096 + tid * 16;
            int row = L >> 8;
            int ss = ((L >> 4) & 15) ^ (row & 15);
            gload16(Ab + (size_t)(row0 + row) * strideA + (size_t)k0 * 2 + ss * 16,
                    (char*)As + L);
        }
        #pragma unroll
        for (int r = 0; r < 4; ++r) {
            int L = r * 4096 + tid * 16;
            int row = L >> 8;
            int ss = ((L >> 4) & 15) ^ (row & 15);
            gload16(Bb + (size_t)(col0 + row) * strideA + (size_t)k0 * 2 + ss * 16,
                    (char*)Bs + L);
        }
        __syncthreads();
        #pragma unroll
        for (int kk = 0; kk < 4; ++kk) {
            bf16x8 af[2], bf[4];
            #pragma unroll
            for (int m = 0; m < 2; ++m) {
                int rowa = wave * 32 + m * 16 + fr;
                af[m] = *(const bf16x8*)&As[rowa * 128 + ((kk * 4 + fq) ^ (rowa & 15)) * 8];
            }
            #pragma unroll
            for (int n = 0; n < 4; ++n) {
                int rowb = n * 16 + fr;
                bf[n] = *(const bf16x8*)&Bs[rowb * 128 + ((kk * 4 + fq) ^ (rowb & 15)) * 8];
            }
            #pragma unroll
            for (int m = 0; m < 2; ++m)
                #pragma unroll
                for (int n = 0; n < 4; ++n)
                    acc[m][n] = __builtin_amdgcn_mfma_f32_16x16x32_bf16(af[m], bf[n], acc[m][n], 0, 0, 0);
        }
        __syncthreads();
    }

    if (type < 2) {
        unsigned short* P = (type == 0 ? Qb : Kb) + ((size_t)bh * SEQ) * 64;
        #pragma unroll
        for (int m = 0; m < 2; ++m)
            #pragma unroll
            for (int n = 0; n < 4; ++n) {
                int d = n * 16 + fr;
                int fi = d & 31;
                #pragma unroll
                for (int j = 0; j < 4; ++j) {
                    int s = s0 + wave * 32 + m * 16 + fq * 4 + j;
                    float2 cs = rtab[s * 32 + fi];
                    float val = acc[m][n][j], par = acc[m][n ^ 2][j];
                    float o = (d < 32) ? val * cs.x - par * cs.y
                                       : val * cs.x + par * cs.y;
                    P[(size_t)s * 64 + d] = f2bf(o);
                }
            }
    } else {
        // V: LDS transpose (reuse As region), row stride 136
        unsigned short* vt = As;    // 64*136*2 = 17408 B
        #pragma unroll
        for (int m = 0; m < 2; ++m)
            #pragma unroll
            for (int n = 0; n < 4; ++n) {
                int d = n * 16 + fr;
                #pragma unroll
                for (int j = 0; j < 4; ++j)
                    vt[d * 136 + wave * 32 + m * 16 + fq * 4 + j] = f2bf(acc[m][n][j]);
            }
        __syncthreads();
        int d = tid >> 2, sg = tid & 3;
        unsigned short* vrow = Vt + ((size_t)bh * 64 + d) * SEQ + s0 + sg * 32;
        #pragma unroll
        for (int i = 0; i < 4; ++i)
            *(bf16x8*)(vrow + i * 8) = *(const bf16x8*)&vt[d * 136 + sg * 32 + i * 8];
    }
}

// ------ fused FFN-in: 128x64 tile, BK=128, interleaved [wi0|wi1] panel ---
// Fragment n even = wi0, n odd = wi1 (validated interleave); gated GELU
// in-register; output 128x32 of mgate per block. Grid 1152.
__global__ __launch_bounds__(256) void gemm_ffn128i(const unsigned short* __restrict__ A,
                                                    const unsigned short* __restrict__ Bt,
                                                    unsigned short* __restrict__ O) {
    __shared__ unsigned short As[128 * 128];   // 32 KB
    __shared__ unsigned short Bs[64 * 128];    // 16 KB
    int bid = blockIdx.x;                       // 1152 blocks
    int id2 = (bid & 7) * 144 + (bid >> 3);
    int col0 = (id2 % 36) * 64, row0 = (id2 / 36) * 128;   // col0: interleaved rows
    int tid = threadIdx.x;
    int wave = tid >> 6, lane = tid & 63;
    int fr = lane & 15, fq = lane >> 4;

    const size_t strideA = (size_t)768 * 2;
    const char* Ab = (const char*)A;
    const char* Bb = (const char*)Bt;

    f32x4 acc[2][4];
    #pragma unroll
    for (int m = 0; m < 2; ++m)
        #pragma unroll
        for (int n = 0; n < 4; ++n)
            acc[m][n] = (f32x4){0.f, 0.f, 0.f, 0.f};

    for (int t = 0; t < 6; ++t) {
        int k0 = t << 7;
        #pragma unroll
        for (int r = 0; r < 8; ++r) {
            int L = r * 4096 + tid * 16;
            int row = L >> 8;
            int ss = ((L >> 4) & 15) ^ (row & 15);
            gload16(Ab + (size_t)(row0 + row) * strideA + (size_t)k0 * 2 + ss * 16,
                    (char*)As + L);
        }
        #pragma unroll
        for (int r = 0; r < 4; ++r) {
            int L = r * 4096 + tid * 16;
            int row = L >> 8;
            int ss = ((L >> 4) & 15) ^ (row & 15);
            gload16(Bb + (size_t)(col0 + row) * strideA + (size_t)k0 * 2 + ss * 16,
                    (char*)Bs + L);
        }
        __syncthreads();
        #pragma unroll
        for (int kk = 0; kk < 4; ++kk) {
            bf16x8 af[2], bf[4];
            #pragma unroll
            for (int m = 0; m < 2; ++m) {
                int rowa = wave * 32 + m * 16 + fr;
                af[m] = *(const bf16x8*)&As[rowa * 128 + ((kk * 4 + fq) ^ (rowa & 15)) * 8];
            }
            #pragma unroll
            for (int n = 0; n < 4; ++n) {
                int rowb = n * 16 + fr;
                bf[n] = *(const bf16x8*)&Bs[rowb * 128 + ((kk * 4 + fq) ^ (rowb & 15)) * 8];
            }
            #pragma unroll
            for (int m = 0; m < 2; ++m)
                #pragma unroll
                for (int n = 0; n < 4; ++n)
                    acc[m][n] = __builtin_amdgcn_mfma_f32_16x16x32_bf16(af[m], bf[n], acc[m][n], 0, 0, 0);
        }
        __syncthreads();
    }

    // pair (n, n+1) = (wi0 val, wi1 val); out col = col0/2 + (n>>1)*16 + fr
    #pragma unroll
    for (int m = 0; m < 2; ++m)
        #pragma unroll
        for (int np = 0; np < 4; np += 2)
            #pragma unroll
            for (int j = 0; j < 4; ++j) {
                int r = row0 + wave * 32 + m * 16 + fq * 4 + j;
                float xa = acc[m][np][j];
                float tn = tanhf(0.7978845608028654f * (xa + 0.044715f * xa * xa * xa));
                float gv = 0.5f * xa * (1.f + tn) * acc[m][np + 1][j];
                int col = (col0 >> 1) + (np >> 1) * 16 + fr;
                O[(size_t)r * INTER + col] = f2bf(gv);
            }
}

// ---------------- MFMA sliding-window attention ---------------------------
// XCD-chunk swizzle: adjacent query tiles of same head share K/V -> same L2.
__global__ __launch_bounds__(256) void attn_mfma(const unsigned short* __restrict__ Qb,
                                                 const unsigned short* __restrict__ Kb,
                                                 const unsigned short* __restrict__ Vt,
                                                 const int* __restrict__ pmask,
                                                 unsigned short* __restrict__ ao) {
    __shared__ unsigned short Ks[KTA * 64];     // 24576 B; becomes Ps after QK^T
    __shared__ unsigned short Vs[64 * KTA];     // 24576 B
    __shared__ float pmsk[KTA];

    int bid = blockIdx.x;
    int id2 = (bid & 7) * 96 + (bid >> 3);      // 768 blocks, bijective
    int qt = id2 & 31;
    int h  = (id2 >> 5) % NHEADS;
    int b  = id2 / (32 * NHEADS);
    int bh = b * NHEADS + h;
    int q0 = qt * QTA;
    int kstart = q0 - 64;
    int tid = threadIdx.x;
    int wave = tid >> 6, lane = tid & 63;
    int fr = lane & 15, fq = lane >> 4;

    const unsigned short* Kg = Kb + ((size_t)bh * SEQ) * 64;
    const unsigned short* Vg = Vt + ((size_t)bh * 64) * SEQ;

    const unsigned short* Qg = Qb + ((size_t)bh * SEQ + q0 + wave * 16 + fr) * 64 + fq * 8;
    bf16x8 qf0 = *(const bf16x8*)(Qg);
    bf16x8 qf1 = *(const bf16x8*)(Qg + 32);
    if (tid < KTA) {
        int k = kstart + tid;
        pmsk[tid] = (k >= 0 && k < SEQ) ? (1.0f - (float)pmask[b * SEQ + k]) * -1e9f
                                        : -1e9f;
    }

    bool interior = (qt != 0) && (qt != 31);
    if (interior) {
        #pragma unroll
        for (int r = 0; r < 6; ++r) {
            int c = r * 256 + tid;
            int row = c >> 3, slot = c & 7;
            int ss = slot ^ (row & 7);
            gload16(Kg + (size_t)(kstart + row) * 64 + ss * 8, (char*)Ks + c * 16);
        }
        #pragma unroll
        for (int r = 0; r < 6; ++r) {
            int c = r * 256 + tid;
            int d = c / 24, slot = c - d * 24;
            int ss = (slot & ~7) | ((slot & 7) ^ (d & 7));
            gload16(Vg + (size_t)d * SEQ + kstart + ss * 8, (char*)Vs + c * 16);
        }
    } else {
        #pragma unroll
        for (int r = 0; r < 6; ++r) {
            int c = r * 256 + tid;
            int row = c >> 3, slot = c & 7;
            int ss = slot ^ (row & 7);
            int sk = kstart + row;
            bf16x8 val = {0, 0, 0, 0, 0, 0, 0, 0};
            if (sk >= 0 && sk < SEQ)
                val = *(const bf16x8*)(Kg + (size_t)sk * 64 + ss * 8);
            *(bf16x8*)((char*)Ks + c * 16) = val;
        }
        #pragma unroll
        for (int r = 0; r < 6; ++r) {
            int c = r * 256 + tid;
            int d = c / 24, slot = c - d * 24;
            int ss = (slot & ~7) | ((slot & 7) ^ (d & 7));
            int start = kstart + ss * 8;
            bf16x8 val = {0, 0, 0, 0, 0, 0, 0, 0};
            if (start >= 0 && start + 8 <= SEQ)
                val = *(const bf16x8*)(Vg + (size_t)d * SEQ + start);
            *(bf16x8*)((char*)Vs + c * 16) = val;
        }
    }
    __syncthreads();

    f32x4 sc[9];
    #pragma unroll
    for (int ni = 0; ni < 9; ++ni) sc[ni] = (f32x4){0.f, 0.f, 0.f, 0.f};
    #pragma unroll
    for (int ni = 0; ni < 9; ++ni) {
        int row = (wave + ni) * 16 + fr;
        int base = row * 64;
        bf16x8 k0 = *(const bf16x8*)&Ks[base + ((fq)     ^ (row & 7)) * 8];
        bf16x8 k1 = *(const bf16x8*)&Ks[base + ((4 + fq) ^ (row & 7)) * 8];
        sc[ni] = __builtin_amdgcn_mfma_f32_16x16x32_bf16(qf0, k0, sc[ni], 0, 0, 0);
        sc[ni] = __builtin_amdgcn_mfma_f32_16x16x32_bf16(qf1, k1, sc[ni], 0, 0, 0);
    }

    int qrow_base = q0 + wave * 16 + fq * 4;
    float mj[4] = {-1e30f, -1e30f, -1e30f, -1e30f}, sj[4];
    #pragma unroll
    for (int ni = 0; ni < 9; ++ni) {
        int kp = (wave + ni) * 16 + fr;
        int k = kstart + kp;
        float pm = pmsk[kp];
        #pragma unroll
        for (int j = 0; j < 4; ++j) {
            int diff = qrow_base + j - k;
            float s = sc[ni][j] * 0.125f + pm;
            if (diff > 64 || diff < -64) s = -1e30f;
            sc[ni][j] = s;
            mj[j] = fmaxf(mj[j], s);
        }
    }
    #pragma unroll
    for (int j = 0; j < 4; ++j) {
        #pragma unroll
        for (int mk = 1; mk < 16; mk <<= 1)
            mj[j] = fmaxf(mj[j], __shfl_xor(mj[j], mk, 16));
        sj[j] = 0.f;
    }
    #pragma unroll
    for (int ni = 0; ni < 9; ++ni)
        #pragma unroll
        for (int j = 0; j < 4; ++j) {
            float e = expf(sc[ni][j] - mj[j]);
            sc[ni][j] = e;
            sj[j] += e;
        }
    #pragma unroll
    for (int j = 0; j < 4; ++j)
        #pragma unroll
        for (int mk = 1; mk < 16; mk <<= 1)
            sj[j] += __shfl_xor(sj[j], mk, 16);

    __syncthreads();   // all waves done reading Ks -> safe to alias as Ps

    unsigned short* Pw = Ks + wave * 16 * KTA;
    #pragma unroll
    for (int ni = 0; ni < 9; ++ni) {
        int n = wave + ni;
        int slot = n * 2 + (fr >> 3);
        #pragma unroll
        for (int j = 0; j < 4; ++j) {
            int row = fq * 4 + j;
            int ss = (slot & ~7) | ((slot & 7) ^ (row & 7));
            Pw[row * KTA + ss * 8 + (fr & 7)] = f2bf(sc[ni][j]);
        }
    }
    #pragma unroll
    for (int n = 0; n < 12; ++n) {
        if (n >= wave && n <= wave + 8) continue;
        int slot = n * 2 + (fr >> 3);
        #pragma unroll
        for (int j = 0; j < 4; ++j) {
            int row = fq * 4 + j;
            int ss = (slot & ~7) | ((slot & 7) ^ (row & 7));
            Pw[row * KTA + ss * 8 + (fr & 7)] = 0;
        }
    }

    f32x4 oacc[4];
    #pragma unroll
    for (int n = 0; n < 4; ++n) oacc[n] = (f32x4){0.f, 0.f, 0.f, 0.f};
    int kt0 = wave >> 1;
    #pragma unroll
    for (int ki = 0; ki < 5; ++ki) {
        int slot = (kt0 + ki) * 4 + fq;
        int ssp = (slot & ~7) | ((slot & 7) ^ (fr & 7));
        bf16x8 pa = *(const bf16x8*)&Pw[fr * KTA + ssp * 8];
        #pragma unroll
        for (int n = 0; n < 4; ++n) {
            int d = n * 16 + fr;
            int ssv = (slot & ~7) | ((slot & 7) ^ (d & 7));
            bf16x8 vf = *(const bf16x8*)&Vs[d * KTA + ssv * 8];
            oacc[n] = __builtin_amdgcn_mfma_f32_16x16x32_bf16(pa, vf, oacc[n], 0, 0, 0);
        }
    }

    unsigned short* aob = ao + ((size_t)(b * SEQ + qrow_base)) * HID + h * 64;
    float rs[4];
    #pragma unroll
    for (int j = 0; j < 4; ++j) rs[j] = 1.0f / sj[j];
    #pragma unroll
    for (int n = 0; n < 4; ++n)
        #pragma unroll
        for (int j = 0; j < 4; ++j)
            aob[(size_t)j * HID + n * 16 + fr] = f2bf(oacc[n][j] * rs[j]);
}

extern "C" void kernel_launch(void* const* d_in, const int* in_sizes, int n_in,
                              void* d_out, int out_size, void* d_ws, size_t ws_size,
                              hipStream_t stream) {
    const float* x       = (const float*)d_in[0];
    const int*   pmask   = (const int*)d_in[1];
    const float* wqkv    = (const float*)d_in[2];
    const float* wo_attn = (const float*)d_in[3];
    const float* wi0     = (const float*)d_in[4];
    const float* wi1     = (const float*)d_in[5];
    const float* wo_mlp  = (const float*)d_in[6];
    const float* g_attn  = (const float*)d_in[7];
    const float* g_mlp   = (const float*)d_in[8];
    float* out = (float*)d_out;

    char* w = (char*)d_ws;
    unsigned short* hbf   = (unsigned short*)(w);              // 6291456 B
    unsigned short* aobf  = (unsigned short*)(w + 6291456);    // 6291456 B
    unsigned short* Qb    = (unsigned short*)(w + 12582912);   // 6291456 B
    unsigned short* Kb    = (unsigned short*)(w + 18874368);   // 6291456 B
    unsigned short* Vt    = (unsigned short*)(w + 25165824);   // 6291456 B
    unsigned short* mgate = (unsigned short*)(w + 31457280);   // 9437184 B
    float2*         rtab  = (float2*)(w + 40894464);           // 524288 B
    unsigned short* wqkvT = (unsigned short*)(w + 41418752);   // [2304][768]
    unsigned short* woaT  = (unsigned short*)(w + 44957696);   // [768][768]
    unsigned short* wiT   = (unsigned short*)(w + 46137344);   // [2304][768] interleaved
    unsigned short* womT  = (unsigned short*)(w + 49676288);   // [768][1152]

    // 0. merged: rmsnorm1 + weight transposes (wi interleaved) + rope table
    prep_rms_kernel<<<4096 + 5152, 256, 0, stream>>>(x, g_attn, hbf,
                                                     wqkv, wo_attn, wi0, wi1, wo_mlp,
                                                     wqkvT, woaT, wiT, womT, rtab);
    // 1. fused qkv GEMM + RoPE + layout -> Qb, Kb, Vt
    gemm_qkv128<<<1152, 256, 0, stream>>>(hbf, wqkvT, rtab, Qb, Kb, Vt);
    // 2. MFMA sliding-window attention
    attn_mfma<<<NB * NHEADS * (SEQ / QTA), 256, 0, stream>>>(Qb, Kb, Vt, pmask, aobf);
    // 3. x1 = x + ao @ wo_attn  -> d_out
    gemm_wo128<<<384, 256, 0, stream>>>(aobf, woaT, x, out, 768, 768);
    // 4. h = rmsnorm(x1, g_mlp)
    rmsnorm_kernel<<<ROWS, 256, 0, stream>>>(out, g_mlp, hbf);
    // 5. mgate = gelu(h@wi0) * (h@wi1)  (interleaved panel, proven engine)
    gemm_ffn128i<<<1152, 256, 0, stream>>>(hbf, wiT, mgate);
    // 6. out = x1 + mgate @ wo_mlp
    gemm_wo128<<<384, 256, 0, stream>>>(mgate, womT, out, out, 768, 1152);
}